// Round 3
// baseline (90.683 us; speedup 1.0000x reference)
//
#include <hip/hip_runtime.h>
#include <math.h>

#define BB 4
#define LL 512
#define NROW (BB*LL)      // 2048
#define DD 128
#define DEG 511.0f
#define SCALE 0.08838834764831845f   // 1/sqrt(128)

typedef short bf16x8 __attribute__((ext_vector_type(8)));
typedef float f32x4 __attribute__((ext_vector_type(4)));

static __device__ __forceinline__ ushort f2bf(float f) {
  unsigned u = __float_as_uint(f);
  u = (u + 0x7fffu + ((u >> 16) & 1u)) >> 16;   // RNE
  return (ushort)u;
}

// ---------------- K1: embed + 6 projections + colsum(x) partials + counter zero ----------------
__global__ __launch_bounds__(256) void k_front(
    const float* __restrict__ inputs, const float* __restrict__ coords,
    const float* __restrict__ cc,
    const float* __restrict__ Wc, const float* __restrict__ bc,
    const float* __restrict__ Wcc, const float* __restrict__ bcc,
    const float* __restrict__ Wa, const float* __restrict__ ba,
    const float* __restrict__ Wb, const float* __restrict__ bb,
    const float* __restrict__ W1l, const float* __restrict__ W1r,
    ushort* __restrict__ bfA, ushort* __restrict__ bfB,
    ushort* __restrict__ bfAc, ushort* __restrict__ bfBc,
    float* __restrict__ P, float* __restrict__ Q,
    float* __restrict__ xpart, unsigned* __restrict__ cnt) {
  int bx = blockIdx.x, m = blockIdx.y;
  int t = threadIdx.x;
  if (m == 0 && bx == 0 && t < 2) cnt[t] = 0u;   // zero last-block counters for K2/K3
  int row0 = bx * 16;
  int b = bx >> 5;
  __shared__ float fin1[16][12], fin2[16][12];
  __shared__ float Es[16][132];
  __shared__ float cs[2][128];
  if (t < 192) {
    int r = t / 12, k = t % 12;
    int row = row0 + r;
    float v1, v2;
    if (k < 10) {
      float v = inputs[row*10 + k];
      v1 = v;
      v2 = v - inputs[(b*LL)*10 + k];
    } else {
      v1 = coords[row*2 + (k-10)];
      v2 = cc[row*2 + (k-10)];
    }
    fin1[r][k] = v1;
    fin2[r][k] = v2;
  }
  __syncthreads();
  for (int it = 0; it < 8; ++it) {
    int idx = t + it*256;
    int r = idx >> 7, d = idx & 127;
    float e;
    if (m == 0) {
      e = bc[d];
#pragma unroll
      for (int k = 0; k < 12; ++k) e += fin1[r][k] * Wc[k*DD + d];
    } else if (m == 1) {
      e = bcc[d];
#pragma unroll
      for (int k = 0; k < 12; ++k) e += fin2[r][k] * Wcc[k*DD + d];
    } else {
      float e1 = bc[d], e2 = bcc[d];
#pragma unroll
      for (int k = 0; k < 12; ++k) {
        e1 += fin1[r][k] * Wc[k*DD + d];
        e2 += fin2[r][k] * Wcc[k*DD + d];
      }
      e = e1 - e2;
    }
    Es[r][d] = e;
  }
  __syncthreads();
  if (m == 2) {   // colsum(x) partial over these 16 rows
    int d = t & 127, h = t >> 7;
    float s = 0.f;
#pragma unroll
    for (int r = 0; r < 8; ++r) s += Es[h*8 + r][d];
    cs[h][d] = s;
    __syncthreads();
    if (h == 0) xpart[bx*DD + d] = cs[0][d] + cs[1][d];
  }
  const float* U = (m == 2) ? W1l : Wa;
  const float* V = (m == 2) ? W1r : Wb;
  int tx = t & 31, ty = t >> 5;
  int d0 = tx*4, r0 = ty*2;
  float aU0[4]={0,0,0,0}, aU1[4]={0,0,0,0}, aV0[4]={0,0,0,0}, aV1[4]={0,0,0,0};
#pragma unroll 4
  for (int k = 0; k < DD; ++k) {
    float4 u = *(const float4*)&U[k*DD + d0];
    float4 v = *(const float4*)&V[k*DD + d0];
    float e0 = Es[r0][k], e1 = Es[r0+1][k];
    aU0[0]+=e0*u.x; aU0[1]+=e0*u.y; aU0[2]+=e0*u.z; aU0[3]+=e0*u.w;
    aU1[0]+=e1*u.x; aU1[1]+=e1*u.y; aU1[2]+=e1*u.z; aU1[3]+=e1*u.w;
    aV0[0]+=e0*v.x; aV0[1]+=e0*v.y; aV0[2]+=e0*v.z; aV0[3]+=e0*v.w;
    aV1[0]+=e1*v.x; aV1[1]+=e1*v.y; aV1[2]+=e1*v.z; aV1[3]+=e1*v.w;
  }
  if (m < 2) {
    float4 bu = *(const float4*)&ba[d0];
    float4 bw = *(const float4*)&bb[d0];
    ushort* dU = (m == 0) ? bfA : bfAc;
    ushort* dV = (m == 0) ? bfB : bfBc;
    ushort4 o;
    o = make_ushort4(f2bf(aU0[0]+bu.x), f2bf(aU0[1]+bu.y), f2bf(aU0[2]+bu.z), f2bf(aU0[3]+bu.w));
    *(ushort4*)&dU[(row0+r0)*DD + d0] = o;
    o = make_ushort4(f2bf(aU1[0]+bu.x), f2bf(aU1[1]+bu.y), f2bf(aU1[2]+bu.z), f2bf(aU1[3]+bu.w));
    *(ushort4*)&dU[(row0+r0+1)*DD + d0] = o;
    o = make_ushort4(f2bf(aV0[0]+bw.x), f2bf(aV0[1]+bw.y), f2bf(aV0[2]+bw.z), f2bf(aV0[3]+bw.w));
    *(ushort4*)&dV[(row0+r0)*DD + d0] = o;
    o = make_ushort4(f2bf(aV1[0]+bw.x), f2bf(aV1[1]+bw.y), f2bf(aV1[2]+bw.z), f2bf(aV1[3]+bw.w));
    *(ushort4*)&dV[(row0+r0+1)*DD + d0] = o;
  } else {
    *(float4*)&P[(row0+r0)*DD + d0]   = make_float4(aU0[0],aU0[1],aU0[2],aU0[3]);
    *(float4*)&P[(row0+r0+1)*DD + d0] = make_float4(aU1[0],aU1[1],aU1[2],aU1[3]);
    *(float4*)&Q[(row0+r0)*DD + d0]   = make_float4(aV0[0],aV0[1],aV0[2],aV0[3]);
    *(float4*)&Q[(row0+r0+1)*DD + d0] = make_float4(aV1[0],aV1[1],aV1[2],aV1[3]);
  }
}

// ---------------- K2: MFMA adjacency + last-block tail (argmin finalize, diff, sb, targets) ----------------
__global__ __launch_bounds__(256) void k_adj(
    const ushort* __restrict__ bfA, const ushort* __restrict__ bfB,
    const ushort* __restrict__ bfAc, const ushort* __restrict__ bfBc,
    float* __restrict__ diffpart, float* __restrict__ minval, int* __restrict__ minidx,
    const float* __restrict__ targets, const float* __restrict__ xpart,
    const float* __restrict__ W1l,
    int* __restrict__ amin, float* __restrict__ sb, float* __restrict__ out,
    unsigned* __restrict__ cnt) {
  __shared__ ushort Bs[64][136], Bcs[64][136];
  __shared__ float red[256];
  __shared__ float cs2[2][128];
  __shared__ float xs[128];
  __shared__ unsigned done_s;
  int t = threadIdx.x;
  int ix = blockIdx.x, jy = blockIdx.y, b = blockIdx.z;
  int i0 = b*LL + ix*64, j0 = b*LL + jy*64;
  int wave = t >> 6, lane = t & 63;
  int rowA = i0 + wave*16 + (lane & 15);
  int koff = (lane >> 4) * 8;
  bf16x8 av[4], acv[4];
#pragma unroll
  for (int ks = 0; ks < 4; ++ks) {
    av[ks]  = *(const bf16x8*)&bfA[(size_t)rowA*DD + ks*32 + koff];
    acv[ks] = *(const bf16x8*)&bfAc[(size_t)rowA*DD + ks*32 + koff];
  }
  for (int it = 0; it < 4; ++it) {
    int chunk = t + it*256;
    int row = chunk >> 4, c = chunk & 15;
    *(uint4*)&Bs[row][c*8]  = *(const uint4*)&bfB[(size_t)(j0+row)*DD + c*8];
    *(uint4*)&Bcs[row][c*8] = *(const uint4*)&bfBc[(size_t)(j0+row)*DD + c*8];
  }
  __syncthreads();
  f32x4 zf = {0.f, 0.f, 0.f, 0.f};
  f32x4 acc[4], accc[4];
#pragma unroll
  for (int jt = 0; jt < 4; ++jt) { acc[jt] = zf; accc[jt] = zf; }
#pragma unroll
  for (int ks = 0; ks < 4; ++ks) {
#pragma unroll
    for (int jt = 0; jt < 4; ++jt) {
      bf16x8 bv  = *(const bf16x8*)&Bs[jt*16 + (lane&15)][ks*32 + koff];
      bf16x8 bcv = *(const bf16x8*)&Bcs[jt*16 + (lane&15)][ks*32 + koff];
      acc[jt]  = __builtin_amdgcn_mfma_f32_16x16x32_bf16(av[ks],  bv,  acc[jt],  0,0,0);
      accc[jt] = __builtin_amdgcn_mfma_f32_16x16x32_bf16(acv[ks], bcv, accc[jt], 0,0,0);
    }
  }
  // epilogue: C row = (lane>>4)*4 + reg, col = lane&15
  int g = lane >> 4, c = lane & 15;
  float sq = 0.f;
#pragma unroll
  for (int r = 0; r < 4; ++r) {
    float mn = INFINITY; int mi = -1;
#pragma unroll
    for (int jt = 0; jt < 4; ++jt) {
      float v  = acc[jt][r]  * SCALE;
      float vc = accc[jt][r] * SCALE;
      float d = v - vc;
      sq += d*d;
      int j = j0 + jt*16 + c;
      if (v < mn || (v == mn && j > mi)) { mn = v; mi = j; }
    }
#pragma unroll
    for (int msk = 1; msk < 16; msk <<= 1) {
      float ov = __shfl_xor(mn, msk);
      int   oi = __shfl_xor(mi, msk);
      if (ov < mn || (ov == mn && oi > mi)) { mn = ov; mi = oi; }
    }
    if (c == 0) {
      int gi = i0 + wave*16 + g*4 + r;
      minval[gi*8 + jy] = mn;
      minidx[gi*8 + jy] = mi;
    }
  }
  red[t] = sq;
  __syncthreads();
  for (int off = 128; off > 0; off >>= 1) {
    if (t < off) red[t] += red[t+off];
    __syncthreads();
  }
  if (t == 0) diffpart[(b*8 + jy)*8 + ix] = red[0];

  // ---- last-block tail ----
  __threadfence();
  if (t == 0) done_s = atomicAdd(cnt, 1u);
  __syncthreads();
  if (done_s == 255u) {
    __threadfence();   // invalidate caches -> see all other blocks' writes
    // argmin finalize
    for (int row = t; row < NROW; row += 256) {
      float mv = minval[row*8]; int mi = minidx[row*8];
#pragma unroll
      for (int ch = 1; ch < 8; ++ch) {
        float v = minval[row*8+ch]; int i2 = minidx[row*8+ch];
        if (v < mv || (v == mv && i2 > mi)) { mv = v; mi = i2; }
      }
      amin[row] = mi;
    }
    // diff finalize
    red[t] = diffpart[t];
    __syncthreads();
    for (int off = 128; off > 0; off >>= 1) {
      if (t < off) red[t] += red[t+off];
      __syncthreads();
    }
    if (t == 0) out[4] = red[0] / (float)((float)BB*LL*LL);
    if (t < 4) out[5+t] = targets[t*LL];
    // sb GEMV per batch
    int d = t & 127, h = t >> 7;
    for (int b2 = 0; b2 < 4; ++b2) {
      float s = 0.f;
      for (int i = 0; i < 16; ++i) s += xpart[(b2*32 + h*16 + i)*DD + d];
      cs2[h][d] = s;
      __syncthreads();
      if (h == 0) xs[d] = cs2[0][d] + cs2[1][d];
      __syncthreads();
      float acc2 = 0.f;
      for (int k = 0; k < 64; ++k) acc2 += xs[h*64 + k] * W1l[(h*64 + k)*DD + d];
      cs2[h][d] = acc2;
      __syncthreads();
      if (h == 0) sb[b2*DD + d] = cs2[0][d] + cs2[1][d];
      __syncthreads();
    }
  }
}

// ---------------- K3: h1 + colsum partials + last-block final layer ----------------
__global__ __launch_bounds__(256) void k_h1(
    const float* __restrict__ P, const float* __restrict__ Q,
    const float* __restrict__ sb, const float* __restrict__ b1l,
    const int* __restrict__ amin, float* __restrict__ h1,
    float* __restrict__ h1part,
    const float* __restrict__ W2l, const float* __restrict__ b2l,
    const float* __restrict__ W2r, float* __restrict__ out,
    unsigned* __restrict__ cnt) {
  int bx = blockIdx.x, t = threadIdx.x;
  int d = t & 127, h = t >> 7;
  int b = bx >> 4;
  __shared__ float cs[2][128];
  __shared__ float redf[128];
  __shared__ unsigned done_s;
  float base = sb[b*DD + d] * (1.0f/DEG) + b1l[d];
  int4 am4[4];
#pragma unroll
  for (int q = 0; q < 4; ++q) am4[q] = *(const int4*)&amin[bx*32 + h*16 + q*4];
  float ps = 0.f;
#pragma unroll 4
  for (int rr = 0; rr < 16; ++rr) {
    int i = bx*32 + h*16 + rr;
    int am = ((const int*)am4)[rr];
    float v = base - P[am*DD + d] * (1.0f/DEG) + Q[i*DD + d];
    v = fmaxf(v, 0.f);
    h1[i*DD + d] = v;
    ps += v;
  }
  cs[h][d] = ps;
  __syncthreads();
  if (h == 0) h1part[bx*DD + d] = cs[0][d] + cs[1][d];

  // ---- last-block final layer ----
  __threadfence();
  if (t == 0) done_s = atomicAdd(cnt, 1u);
  __syncthreads();
  if (done_s == 63u) {
    __threadfence();
    for (int b2 = 0; b2 < 4; ++b2) {
      if (t < 128) {
        float s = 0.f;
#pragma unroll
        for (int p = 0; p < 16; ++p) s += h1part[(b2*16 + p)*DD + t];
        int am = amin[b2*LL];
        float agg = (s - h1[am*DD + t]) * (1.0f/DEG);
        redf[t] = agg * W2l[t] + h1[(b2*LL)*DD + t] * W2r[t];
      }
      __syncthreads();
      for (int off = 64; off > 0; off >>= 1) {
        if (t < off) redf[t] += redf[t+off];
        __syncthreads();
      }
      if (t == 0) out[b2] = redf[0] + b2l[0];
      __syncthreads();
    }
  }
}

extern "C" void kernel_launch(void* const* d_in, const int* in_sizes, int n_in,
                              void* d_out, int out_size, void* d_ws, size_t ws_size,
                              hipStream_t stream) {
  const float* inputs  = (const float*)d_in[0];
  const float* coords  = (const float*)d_in[1];
  const float* targets = (const float*)d_in[2];
  const float* cc      = (const float*)d_in[3];
  const float* Wc  = (const float*)d_in[5];
  const float* bc  = (const float*)d_in[6];
  const float* Wcc = (const float*)d_in[7];
  const float* bcc = (const float*)d_in[8];
  const float* Wa  = (const float*)d_in[9];
  const float* ba  = (const float*)d_in[10];
  const float* Wb  = (const float*)d_in[11];
  const float* bb  = (const float*)d_in[12];
  const float* W1l = (const float*)d_in[13];
  const float* b1l = (const float*)d_in[14];
  const float* W1r = (const float*)d_in[15];
  const float* W2l = (const float*)d_in[16];
  const float* b2l = (const float*)d_in[17];
  const float* W2r = (const float*)d_in[18];
  float* out = (float*)d_out;

  float* ws = (float*)d_ws;
  float* P  = ws;                               // 262144
  float* Q  = ws + (size_t)NROW*DD;             // 262144
  float* h1 = ws + (size_t)2*NROW*DD;           // 262144
  ushort* bfA  = (ushort*)(ws + (size_t)3*NROW*DD);
  ushort* bfB  = bfA  + (size_t)NROW*DD;
  ushort* bfAc = bfB  + (size_t)NROW*DD;
  ushort* bfBc = bfAc + (size_t)NROW*DD;
  float* xpart    = ws + (size_t)5*NROW*DD;     // 128*128
  float* h1part   = xpart + 128*DD;             // 64*128
  float* sb       = h1part + 64*DD;             // 512
  float* diffpart = sb + 4*DD;                  // 256
  float* minval   = diffpart + 256;             // NROW*8
  int*   minidx   = (int*)(minval + (size_t)NROW*8);
  int*   amin     = minidx + (size_t)NROW*8;    // 2048, 16B-aligned
  unsigned* cnt   = (unsigned*)(amin + NROW);   // 2 counters

  k_front<<<dim3(128, 3), 256, 0, stream>>>(inputs, coords, cc, Wc, bc, Wcc, bcc,
                                            Wa, ba, Wb, bb, W1l, W1r,
                                            bfA, bfB, bfAc, bfBc, P, Q, xpart, cnt);
  k_adj  <<<dim3(8, 8, 4), 256, 0, stream>>>(bfA, bfB, bfAc, bfBc, diffpart, minval, minidx,
                                             targets, xpart, W1l, amin, sb, out, cnt);
  k_h1   <<<64, 256, 0, stream>>>(P, Q, sb, b1l, amin, h1, h1part,
                                  W2l, b2l, W2r, out, cnt + 1);
}

// Round 4
// 60.650 us; speedup vs baseline: 1.4952x; 1.4952x over previous
//
#include <hip/hip_runtime.h>
#include <math.h>

#define BB 4
#define LL 512
#define NROW (BB*LL)      // 2048
#define DD 128
#define DEG 511.0f
#define SCALE 0.08838834764831845f   // 1/sqrt(128)

typedef short bf16x8 __attribute__((ext_vector_type(8)));
typedef float f32x4 __attribute__((ext_vector_type(4)));

static __device__ __forceinline__ ushort f2bf(float f) {
  unsigned u = __float_as_uint(f);
  u = (u + 0x7fffu + ((u >> 16) & 1u)) >> 16;   // RNE
  return (ushort)u;
}

// ---------------- K1: embed + 6 projections + colsum(x) partials ----------------
__global__ __launch_bounds__(256) void k_front(
    const float* __restrict__ inputs, const float* __restrict__ coords,
    const float* __restrict__ cc,
    const float* __restrict__ Wc, const float* __restrict__ bc,
    const float* __restrict__ Wcc, const float* __restrict__ bcc,
    const float* __restrict__ Wa, const float* __restrict__ ba,
    const float* __restrict__ Wb, const float* __restrict__ bb,
    const float* __restrict__ W1l, const float* __restrict__ W1r,
    ushort* __restrict__ bfA, ushort* __restrict__ bfB,
    ushort* __restrict__ bfAc, ushort* __restrict__ bfBc,
    float* __restrict__ P, float* __restrict__ Q,
    float* __restrict__ xpart) {
  int bx = blockIdx.x, m = blockIdx.y;
  int t = threadIdx.x;
  int row0 = bx * 16;
  int b = bx >> 5;
  __shared__ float fin1[16][12], fin2[16][12];
  __shared__ float Es[16][132];
  __shared__ float cs[2][128];
  if (t < 192) {
    int r = t / 12, k = t % 12;
    int row = row0 + r;
    float v1, v2;
    if (k < 10) {
      float v = inputs[row*10 + k];
      v1 = v;
      v2 = v - inputs[(b*LL)*10 + k];
    } else {
      v1 = coords[row*2 + (k-10)];
      v2 = cc[row*2 + (k-10)];
    }
    fin1[r][k] = v1;
    fin2[r][k] = v2;
  }
  __syncthreads();
  for (int it = 0; it < 8; ++it) {
    int idx = t + it*256;
    int r = idx >> 7, d = idx & 127;
    float e;
    if (m == 0) {
      e = bc[d];
#pragma unroll
      for (int k = 0; k < 12; ++k) e += fin1[r][k] * Wc[k*DD + d];
    } else if (m == 1) {
      e = bcc[d];
#pragma unroll
      for (int k = 0; k < 12; ++k) e += fin2[r][k] * Wcc[k*DD + d];
    } else {
      float e1 = bc[d], e2 = bcc[d];
#pragma unroll
      for (int k = 0; k < 12; ++k) {
        e1 += fin1[r][k] * Wc[k*DD + d];
        e2 += fin2[r][k] * Wcc[k*DD + d];
      }
      e = e1 - e2;
    }
    Es[r][d] = e;
  }
  __syncthreads();
  if (m == 2) {   // colsum(x) partial over these 16 rows
    int d = t & 127, h = t >> 7;
    float s = 0.f;
#pragma unroll
    for (int r = 0; r < 8; ++r) s += Es[h*8 + r][d];
    cs[h][d] = s;
    __syncthreads();
    if (h == 0) xpart[bx*DD + d] = cs[0][d] + cs[1][d];
  }
  const float* U = (m == 2) ? W1l : Wa;
  const float* V = (m == 2) ? W1r : Wb;
  int tx = t & 31, ty = t >> 5;
  int d0 = tx*4, r0 = ty*2;
  float aU0[4]={0,0,0,0}, aU1[4]={0,0,0,0}, aV0[4]={0,0,0,0}, aV1[4]={0,0,0,0};
#pragma unroll 4
  for (int k = 0; k < DD; ++k) {
    float4 u = *(const float4*)&U[k*DD + d0];
    float4 v = *(const float4*)&V[k*DD + d0];
    float e0 = Es[r0][k], e1 = Es[r0+1][k];
    aU0[0]+=e0*u.x; aU0[1]+=e0*u.y; aU0[2]+=e0*u.z; aU0[3]+=e0*u.w;
    aU1[0]+=e1*u.x; aU1[1]+=e1*u.y; aU1[2]+=e1*u.z; aU1[3]+=e1*u.w;
    aV0[0]+=e0*v.x; aV0[1]+=e0*v.y; aV0[2]+=e0*v.z; aV0[3]+=e0*v.w;
    aV1[0]+=e1*v.x; aV1[1]+=e1*v.y; aV1[2]+=e1*v.z; aV1[3]+=e1*v.w;
  }
  if (m < 2) {
    float4 bu = *(const float4*)&ba[d0];
    float4 bw = *(const float4*)&bb[d0];
    ushort* dU = (m == 0) ? bfA : bfAc;
    ushort* dV = (m == 0) ? bfB : bfBc;
    ushort4 o;
    o = make_ushort4(f2bf(aU0[0]+bu.x), f2bf(aU0[1]+bu.y), f2bf(aU0[2]+bu.z), f2bf(aU0[3]+bu.w));
    *(ushort4*)&dU[(row0+r0)*DD + d0] = o;
    o = make_ushort4(f2bf(aU1[0]+bu.x), f2bf(aU1[1]+bu.y), f2bf(aU1[2]+bu.z), f2bf(aU1[3]+bu.w));
    *(ushort4*)&dU[(row0+r0+1)*DD + d0] = o;
    o = make_ushort4(f2bf(aV0[0]+bw.x), f2bf(aV0[1]+bw.y), f2bf(aV0[2]+bw.z), f2bf(aV0[3]+bw.w));
    *(ushort4*)&dV[(row0+r0)*DD + d0] = o;
    o = make_ushort4(f2bf(aV1[0]+bw.x), f2bf(aV1[1]+bw.y), f2bf(aV1[2]+bw.z), f2bf(aV1[3]+bw.w));
    *(ushort4*)&dV[(row0+r0+1)*DD + d0] = o;
  } else {
    *(float4*)&P[(row0+r0)*DD + d0]   = make_float4(aU0[0],aU0[1],aU0[2],aU0[3]);
    *(float4*)&P[(row0+r0+1)*DD + d0] = make_float4(aU1[0],aU1[1],aU1[2],aU1[3]);
    *(float4*)&Q[(row0+r0)*DD + d0]   = make_float4(aV0[0],aV0[1],aV0[2],aV0[3]);
    *(float4*)&Q[(row0+r0+1)*DD + d0] = make_float4(aV1[0],aV1[1],aV1[2],aV1[3]);
  }
}

// ---------------- K2: MFMA adjacency, full-j per block, no LDS staging, no fences ----------
// grid (16, 4): block = 32 i-rows x all 512 j. 4 waves: wave = (i-half, j-half).
// B fragments loaded directly from L2. amin finalized in-block via LDS merge.
__global__ __launch_bounds__(256) void k_adj(
    const ushort* __restrict__ bfA, const ushort* __restrict__ bfB,
    const ushort* __restrict__ bfAc, const ushort* __restrict__ bfBc,
    float* __restrict__ diffpart, int* __restrict__ amin) {
  int t = threadIdx.x;
  int ix = blockIdx.x;      // 0..15
  int b  = blockIdx.y;      // 0..3
  int i0 = b*LL + ix*32;
  int w = t >> 6, lane = t & 63;
  int isub = w & 1, jh = w >> 1;
  int rowA = i0 + isub*16 + (lane & 15);
  int koff = (lane >> 4) * 8;
  bf16x8 av[4], acv[4];
#pragma unroll
  for (int ks = 0; ks < 4; ++ks) {
    av[ks]  = *(const bf16x8*)&bfA[(size_t)rowA*DD + ks*32 + koff];
    acv[ks] = *(const bf16x8*)&bfAc[(size_t)rowA*DD + ks*32 + koff];
  }
  float mn[4] = {INFINITY, INFINITY, INFINITY, INFINITY};
  int   mi[4] = {-1,-1,-1,-1};
  float sq = 0.f;
  int c = lane & 15, g = lane >> 4;
  for (int jc = jh*4; jc < jh*4 + 4; ++jc) {
    int j0 = b*LL + jc*64;
    f32x4 zf = {0.f,0.f,0.f,0.f};
    f32x4 acc[4], accc[4];
#pragma unroll
    for (int jt = 0; jt < 4; ++jt) { acc[jt] = zf; accc[jt] = zf; }
#pragma unroll
    for (int ks = 0; ks < 4; ++ks) {
#pragma unroll
      for (int jt = 0; jt < 4; ++jt) {
        bf16x8 bv  = *(const bf16x8*)&bfB[(size_t)(j0 + jt*16 + c)*DD + ks*32 + koff];
        bf16x8 bcv = *(const bf16x8*)&bfBc[(size_t)(j0 + jt*16 + c)*DD + ks*32 + koff];
        acc[jt]  = __builtin_amdgcn_mfma_f32_16x16x32_bf16(av[ks],  bv,  acc[jt],  0,0,0);
        accc[jt] = __builtin_amdgcn_mfma_f32_16x16x32_bf16(acv[ks], bcv, accc[jt], 0,0,0);
      }
    }
    // per-chunk epilogue: C row = g*4 + r, col = c
#pragma unroll
    for (int r = 0; r < 4; ++r) {
#pragma unroll
      for (int jt = 0; jt < 4; ++jt) {
        float v  = acc[jt][r]  * SCALE;
        float vc = accc[jt][r] * SCALE;
        float d = v - vc;
        sq += d*d;
        int j = j0 + jt*16 + c;
        if (v < mn[r] || (v == mn[r] && j > mi[r])) { mn[r] = v; mi[r] = j; }
      }
    }
  }
  // cross-lane (16 cols) argmin reduce
#pragma unroll
  for (int r = 0; r < 4; ++r) {
#pragma unroll
    for (int msk = 1; msk < 16; msk <<= 1) {
      float ov = __shfl_xor(mn[r], msk);
      int   oi = __shfl_xor(mi[r], msk);
      if (ov < mn[r] || (ov == mn[r] && oi > mi[r])) { mn[r] = ov; mi[r] = oi; }
    }
  }
  __shared__ float mnS[2][32];
  __shared__ int   miS[2][32];
  if (c == 0) {
#pragma unroll
    for (int r = 0; r < 4; ++r) {
      int rr = isub*16 + g*4 + r;
      mnS[jh][rr] = mn[r];
      miS[jh][rr] = mi[r];
    }
  }
  __shared__ float red[256];
  red[t] = sq;
  __syncthreads();
  for (int off = 128; off > 0; off >>= 1) {
    if (t < off) red[t] += red[t+off];
    __syncthreads();
  }
  if (t == 0) diffpart[b*16 + ix] = red[0];
  if (t < 32) {
    float v0 = mnS[0][t]; int j0_ = miS[0][t];
    float v1 = mnS[1][t]; int j1_ = miS[1][t];
    // all j in half 1 exceed all j in half 0 -> tie (equal) prefers half 1
    amin[i0 + t] = (v1 <= v0) ? j1_ : j0_;
  }
}

// ---------------- K3: per-batch tail: sb GEMV, h1 streamed, final layer, diff, targets ----
__global__ __launch_bounds__(1024) void k_tail(
    const float* __restrict__ P, const float* __restrict__ Q,
    const float* __restrict__ xpart, const float* __restrict__ W1l,
    const float* __restrict__ b1l, const int* __restrict__ amin,
    const float* __restrict__ diffpart, const float* __restrict__ targets,
    const float* __restrict__ W2l, const float* __restrict__ b2l,
    const float* __restrict__ W2r, float* __restrict__ out) {
  int b = blockIdx.x, t = threadIdx.x;
  int d = t & 127, h = t >> 7;     // h: 0..7
  __shared__ float part[8][128];
  __shared__ float xs[128];
  __shared__ float sbv[128];
  // ---- sb = (colsum_b x) @ W1l ----
  float s = 0.f;
#pragma unroll
  for (int i = h; i < 32; i += 8) s += xpart[(b*32 + i)*DD + d];
  part[h][d] = s;
  __syncthreads();
  if (h == 0) {
    float v = 0.f;
#pragma unroll
    for (int q = 0; q < 8; ++q) v += part[q][d];
    xs[d] = v;
  }
  __syncthreads();
  float acc = 0.f;
#pragma unroll
  for (int k = h*16; k < h*16 + 16; ++k) acc += xs[k] * W1l[k*DD + d];
  part[h][d] = acc;
  __syncthreads();
  if (h == 0) {
    float v = 0.f;
#pragma unroll
    for (int q = 0; q < 8; ++q) v += part[q][d];
    sbv[d] = v;
  }
  __syncthreads();
  float base = sbv[d] * (1.0f/DEG) + b1l[d];
  // ---- stream h1 rows, accumulate colsum ----
  float csum = 0.f;
  int r0 = b*LL + h*64;
#pragma unroll 4
  for (int r = 0; r < 64; ++r) {
    int i = r0 + r;
    int am = amin[i];
    float v = base - P[(size_t)am*DD + d] * (1.0f/DEG) + Q[(size_t)i*DD + d];
    csum += fmaxf(v, 0.f);
  }
  part[h][d] = csum;
  __syncthreads();
  if (h == 0) {
    float colsum = 0.f;
#pragma unroll
    for (int q = 0; q < 8; ++q) colsum += part[q][d];
    int head = b*LL;
    int amh = amin[head];
    int am2 = amin[amh];
    float h1head = fmaxf(base - P[(size_t)amh*DD + d]*(1.0f/DEG) + Q[(size_t)head*DD + d], 0.f);
    float h1am   = fmaxf(base - P[(size_t)am2*DD + d]*(1.0f/DEG) + Q[(size_t)amh*DD + d], 0.f);
    float agg = (colsum - h1am) * (1.0f/DEG);
    part[0][d] = agg * W2l[d] + h1head * W2r[d];
  }
  __syncthreads();
  if (t < 64) {
    float v = part[0][t] + part[0][t + 64];
#pragma unroll
    for (int msk = 32; msk > 0; msk >>= 1) v += __shfl_down(v, msk);
    if (t == 0) out[b] = v + b2l[0];
  }
  // ---- diff + targets (block 0) ----
  if (b == 0) {
    if (t >= 128 && t < 192) {
      int q = t - 128;
      float v = diffpart[q];
#pragma unroll
      for (int msk = 32; msk > 0; msk >>= 1) v += __shfl_down(v, msk);
      if (q == 0) out[4] = v / (float)((float)BB*LL*LL);
    }
    if (t >= 192 && t < 196) out[5 + (t-192)] = targets[(t-192)*LL];
  }
}

extern "C" void kernel_launch(void* const* d_in, const int* in_sizes, int n_in,
                              void* d_out, int out_size, void* d_ws, size_t ws_size,
                              hipStream_t stream) {
  const float* inputs  = (const float*)d_in[0];
  const float* coords  = (const float*)d_in[1];
  const float* targets = (const float*)d_in[2];
  const float* cc      = (const float*)d_in[3];
  const float* Wc  = (const float*)d_in[5];
  const float* bc  = (const float*)d_in[6];
  const float* Wcc = (const float*)d_in[7];
  const float* bcc = (const float*)d_in[8];
  const float* Wa  = (const float*)d_in[9];
  const float* ba  = (const float*)d_in[10];
  const float* Wb  = (const float*)d_in[11];
  const float* bb  = (const float*)d_in[12];
  const float* W1l = (const float*)d_in[13];
  const float* b1l = (const float*)d_in[14];
  const float* W1r = (const float*)d_in[15];
  const float* W2l = (const float*)d_in[16];
  const float* b2l = (const float*)d_in[17];
  const float* W2r = (const float*)d_in[18];
  float* out = (float*)d_out;

  float* ws = (float*)d_ws;
  float* P  = ws;                               // NROW*DD
  float* Q  = ws + (size_t)NROW*DD;             // NROW*DD
  ushort* bfA  = (ushort*)(ws + (size_t)2*NROW*DD);
  ushort* bfB  = bfA  + (size_t)NROW*DD;
  ushort* bfAc = bfB  + (size_t)NROW*DD;
  ushort* bfBc = bfAc + (size_t)NROW*DD;
  float* xpart    = ws + (size_t)4*NROW*DD;     // 128*128
  float* diffpart = xpart + 128*DD;             // 64
  int*   amin     = (int*)(diffpart + 64);      // NROW

  k_front<<<dim3(128, 3), 256, 0, stream>>>(inputs, coords, cc, Wc, bc, Wcc, bcc,
                                            Wa, ba, Wb, bb, W1l, W1r,
                                            bfA, bfB, bfAc, bfBc, P, Q, xpart);
  k_adj  <<<dim3(16, 4), 256, 0, stream>>>(bfA, bfB, bfAc, bfBc, diffpart, amin);
  k_tail <<<4, 1024, 0, stream>>>(P, Q, xpart, W1l, b1l, amin, diffpart, targets,
                                  W2l, b2l, W2r, out);
}

// Round 5
// 46.178 us; speedup vs baseline: 1.9638x; 1.3134x over previous
//
#include <hip/hip_runtime.h>
#include <math.h>

#define BB 4
#define LL 512
#define NROW (BB*LL)      // 2048
#define DD 128
#define DEG 511.0f
#define SCALE 0.08838834764831845f   // 1/sqrt(128)

typedef short bf16x8 __attribute__((ext_vector_type(8)));
typedef float f32x4 __attribute__((ext_vector_type(4)));

static __device__ __forceinline__ ushort f2bf(float f) {
  unsigned u = __float_as_uint(f);
  u = (u + 0x7fffu + ((u >> 16) & 1u)) >> 16;   // RNE
  return (ushort)u;
}

// ---------------- K1: embed + 6 projections + colsum(x) partials ----------------
__global__ __launch_bounds__(256) void k_front(
    const float* __restrict__ inputs, const float* __restrict__ coords,
    const float* __restrict__ cc,
    const float* __restrict__ Wc, const float* __restrict__ bc,
    const float* __restrict__ Wcc, const float* __restrict__ bcc,
    const float* __restrict__ Wa, const float* __restrict__ ba,
    const float* __restrict__ Wb, const float* __restrict__ bb,
    const float* __restrict__ W1l, const float* __restrict__ W1r,
    ushort* __restrict__ bfA, ushort* __restrict__ bfB,
    ushort* __restrict__ bfAc, ushort* __restrict__ bfBc,
    float* __restrict__ P, float* __restrict__ Q,
    float* __restrict__ xpart) {
  int bx = blockIdx.x, m = blockIdx.y;
  int t = threadIdx.x;
  int row0 = bx * 16;
  int b = bx >> 5;
  __shared__ float fin1[16][12], fin2[16][12];
  __shared__ float Es[16][132];
  __shared__ float cs[2][128];
  if (t < 192) {
    int r = t / 12, k = t % 12;
    int row = row0 + r;
    float v1, v2;
    if (k < 10) {
      float v = inputs[row*10 + k];
      v1 = v;
      v2 = v - inputs[(b*LL)*10 + k];
    } else {
      v1 = coords[row*2 + (k-10)];
      v2 = cc[row*2 + (k-10)];
    }
    fin1[r][k] = v1;
    fin2[r][k] = v2;
  }
  __syncthreads();
  for (int it = 0; it < 8; ++it) {
    int idx = t + it*256;
    int r = idx >> 7, d = idx & 127;
    float e;
    if (m == 0) {
      e = bc[d];
#pragma unroll
      for (int k = 0; k < 12; ++k) e += fin1[r][k] * Wc[k*DD + d];
    } else if (m == 1) {
      e = bcc[d];
#pragma unroll
      for (int k = 0; k < 12; ++k) e += fin2[r][k] * Wcc[k*DD + d];
    } else {
      float e1 = bc[d], e2 = bcc[d];
#pragma unroll
      for (int k = 0; k < 12; ++k) {
        e1 += fin1[r][k] * Wc[k*DD + d];
        e2 += fin2[r][k] * Wcc[k*DD + d];
      }
      e = e1 - e2;
    }
    Es[r][d] = e;
  }
  __syncthreads();
  if (m == 2) {   // colsum(x) partial over these 16 rows
    int d = t & 127, h = t >> 7;
    float s = 0.f;
#pragma unroll
    for (int r = 0; r < 8; ++r) s += Es[h*8 + r][d];
    cs[h][d] = s;
    __syncthreads();
    if (h == 0) xpart[bx*DD + d] = cs[0][d] + cs[1][d];
  }
  const float* U = (m == 2) ? W1l : Wa;
  const float* V = (m == 2) ? W1r : Wb;
  int tx = t & 31, ty = t >> 5;
  int d0 = tx*4, r0 = ty*2;
  float aU0[4]={0,0,0,0}, aU1[4]={0,0,0,0}, aV0[4]={0,0,0,0}, aV1[4]={0,0,0,0};
#pragma unroll 4
  for (int k = 0; k < DD; ++k) {
    float4 u = *(const float4*)&U[k*DD + d0];
    float4 v = *(const float4*)&V[k*DD + d0];
    float e0 = Es[r0][k], e1 = Es[r0+1][k];
    aU0[0]+=e0*u.x; aU0[1]+=e0*u.y; aU0[2]+=e0*u.z; aU0[3]+=e0*u.w;
    aU1[0]+=e1*u.x; aU1[1]+=e1*u.y; aU1[2]+=e1*u.z; aU1[3]+=e1*u.w;
    aV0[0]+=e0*v.x; aV0[1]+=e0*v.y; aV0[2]+=e0*v.z; aV0[3]+=e0*v.w;
    aV1[0]+=e1*v.x; aV1[1]+=e1*v.y; aV1[2]+=e1*v.z; aV1[3]+=e1*v.w;
  }
  if (m < 2) {
    float4 bu = *(const float4*)&ba[d0];
    float4 bw = *(const float4*)&bb[d0];
    ushort* dU = (m == 0) ? bfA : bfAc;
    ushort* dV = (m == 0) ? bfB : bfBc;
    ushort4 o;
    o = make_ushort4(f2bf(aU0[0]+bu.x), f2bf(aU0[1]+bu.y), f2bf(aU0[2]+bu.z), f2bf(aU0[3]+bu.w));
    *(ushort4*)&dU[(row0+r0)*DD + d0] = o;
    o = make_ushort4(f2bf(aU1[0]+bu.x), f2bf(aU1[1]+bu.y), f2bf(aU1[2]+bu.z), f2bf(aU1[3]+bu.w));
    *(ushort4*)&dU[(row0+r0+1)*DD + d0] = o;
    o = make_ushort4(f2bf(aV0[0]+bw.x), f2bf(aV0[1]+bw.y), f2bf(aV0[2]+bw.z), f2bf(aV0[3]+bw.w));
    *(ushort4*)&dV[(row0+r0)*DD + d0] = o;
    o = make_ushort4(f2bf(aV1[0]+bw.x), f2bf(aV1[1]+bw.y), f2bf(aV1[2]+bw.z), f2bf(aV1[3]+bw.w));
    *(ushort4*)&dV[(row0+r0+1)*DD + d0] = o;
  } else {
    *(float4*)&P[(row0+r0)*DD + d0]   = make_float4(aU0[0],aU0[1],aU0[2],aU0[3]);
    *(float4*)&P[(row0+r0+1)*DD + d0] = make_float4(aU1[0],aU1[1],aU1[2],aU1[3]);
    *(float4*)&Q[(row0+r0)*DD + d0]   = make_float4(aV0[0],aV0[1],aV0[2],aV0[3]);
    *(float4*)&Q[(row0+r0+1)*DD + d0] = make_float4(aV1[0],aV1[1],aV1[2],aV1[3]);
  }
}

// ---------------- K2: MFMA adjacency (R2 core): LDS-staged B, A direct, no fences -------
__global__ __launch_bounds__(256) void k_adj(
    const ushort* __restrict__ bfA, const ushort* __restrict__ bfB,
    const ushort* __restrict__ bfAc, const ushort* __restrict__ bfBc,
    float* __restrict__ diffpart, float* __restrict__ minval, int* __restrict__ minidx) {
  __shared__ ushort Bs[64][136], Bcs[64][136];
  __shared__ float red[256];
  int t = threadIdx.x;
  int ix = blockIdx.x, jy = blockIdx.y, b = blockIdx.z;
  int i0 = b*LL + ix*64, j0 = b*LL + jy*64;
  int wave = t >> 6, lane = t & 63;
  int rowA = i0 + wave*16 + (lane & 15);
  int koff = (lane >> 4) * 8;
  bf16x8 av[4], acv[4];
#pragma unroll
  for (int ks = 0; ks < 4; ++ks) {
    av[ks]  = *(const bf16x8*)&bfA[(size_t)rowA*DD + ks*32 + koff];
    acv[ks] = *(const bf16x8*)&bfAc[(size_t)rowA*DD + ks*32 + koff];
  }
  for (int it = 0; it < 4; ++it) {
    int chunk = t + it*256;
    int row = chunk >> 4, c4 = chunk & 15;
    *(uint4*)&Bs[row][c4*8]  = *(const uint4*)&bfB[(size_t)(j0+row)*DD + c4*8];
    *(uint4*)&Bcs[row][c4*8] = *(const uint4*)&bfBc[(size_t)(j0+row)*DD + c4*8];
  }
  __syncthreads();
  f32x4 zf = {0.f, 0.f, 0.f, 0.f};
  f32x4 acc[4], accc[4];
#pragma unroll
  for (int jt = 0; jt < 4; ++jt) { acc[jt] = zf; accc[jt] = zf; }
#pragma unroll
  for (int ks = 0; ks < 4; ++ks) {
#pragma unroll
    for (int jt = 0; jt < 4; ++jt) {
      bf16x8 bv  = *(const bf16x8*)&Bs[jt*16 + (lane&15)][ks*32 + koff];
      bf16x8 bcv = *(const bf16x8*)&Bcs[jt*16 + (lane&15)][ks*32 + koff];
      acc[jt]  = __builtin_amdgcn_mfma_f32_16x16x32_bf16(av[ks],  bv,  acc[jt],  0,0,0);
      accc[jt] = __builtin_amdgcn_mfma_f32_16x16x32_bf16(acv[ks], bcv, accc[jt], 0,0,0);
    }
  }
  // epilogue: C row = (lane>>4)*4 + reg, col = lane&15
  int g = lane >> 4, c = lane & 15;
  float sq = 0.f;
#pragma unroll
  for (int r = 0; r < 4; ++r) {
    float mn = INFINITY; int mi = -1;
#pragma unroll
    for (int jt = 0; jt < 4; ++jt) {
      float v  = acc[jt][r]  * SCALE;
      float vc = accc[jt][r] * SCALE;
      float d = v - vc;
      sq += d*d;
      int j = j0 + jt*16 + c;
      if (v < mn || (v == mn && j > mi)) { mn = v; mi = j; }
    }
#pragma unroll
    for (int msk = 1; msk < 16; msk <<= 1) {
      float ov = __shfl_xor(mn, msk);
      int   oi = __shfl_xor(mi, msk);
      if (ov < mn || (ov == mn && oi > mi)) { mn = ov; mi = oi; }
    }
    if (c == 0) {
      int gi = i0 + wave*16 + g*4 + r;
      minval[gi*8 + jy] = mn;
      minidx[gi*8 + jy] = mi;
    }
  }
  red[t] = sq;
  __syncthreads();
  for (int off = 128; off > 0; off >>= 1) {
    if (t < off) red[t] += red[t+off];
    __syncthreads();
  }
  if (t == 0) diffpart[(b*8 + jy)*8 + ix] = red[0];
}

// ---------------- K3: per-batch tail: argmin finalize (LDS), sb, h1 stream, final, diff ----
__global__ __launch_bounds__(1024) void k_tail(
    const float* __restrict__ P, const float* __restrict__ Q,
    const float* __restrict__ xpart, const float* __restrict__ W1l,
    const float* __restrict__ b1l,
    const float* __restrict__ minval, const int* __restrict__ minidx,
    const float* __restrict__ diffpart, const float* __restrict__ targets,
    const float* __restrict__ W2l, const float* __restrict__ b2l,
    const float* __restrict__ W2r, float* __restrict__ out) {
  int b = blockIdx.x, t = threadIdx.x;
  int d = t & 127, h = t >> 7;     // h: 0..7
  __shared__ int aminL[LL];        // global row index of argmin, for this batch's rows
  __shared__ float part[8][128];
  __shared__ float xs[128];
  __shared__ float sbv[128];
  // ---- argmin finalize for this batch (block-local) ----
  if (t < LL) {
    int row = b*LL + t;
    float mv = minval[row*8]; int mi = minidx[row*8];
#pragma unroll
    for (int ch = 1; ch < 8; ++ch) {
      float v = minval[row*8 + ch]; int i2 = minidx[row*8 + ch];
      if (v < mv || (v == mv && i2 > mi)) { mv = v; mi = i2; }
    }
    aminL[t] = mi;
  }
  // ---- sb = (colsum_b x) @ W1l ----
  float s = 0.f;
#pragma unroll
  for (int i = h; i < 32; i += 8) s += xpart[(b*32 + i)*DD + d];
  part[h][d] = s;
  __syncthreads();   // covers aminL + part
  if (h == 0) {
    float v = 0.f;
#pragma unroll
    for (int q = 0; q < 8; ++q) v += part[q][d];
    xs[d] = v;
  }
  __syncthreads();
  float acc = 0.f;
#pragma unroll
  for (int k = h*16; k < h*16 + 16; ++k) acc += xs[k] * W1l[k*DD + d];
  part[h][d] = acc;
  __syncthreads();
  if (h == 0) {
    float v = 0.f;
#pragma unroll
    for (int q = 0; q < 8; ++q) v += part[q][d];
    sbv[d] = v;
  }
  __syncthreads();
  float base = sbv[d] * (1.0f/DEG) + b1l[d];
  // ---- stream h1 rows, accumulate colsum ----
  float csum = 0.f;
  int l0 = h*64;
#pragma unroll 4
  for (int r = 0; r < 64; ++r) {
    int li = l0 + r;
    int am = aminL[li];
    float v = base - P[(size_t)am*DD + d] * (1.0f/DEG) + Q[(size_t)(b*LL + li)*DD + d];
    csum += fmaxf(v, 0.f);
  }
  part[h][d] = csum;
  __syncthreads();
  if (h == 0) {
    float colsum = 0.f;
#pragma unroll
    for (int q = 0; q < 8; ++q) colsum += part[q][d];
    int amh = aminL[0];                 // argmin of head row (global index)
    int am2 = aminL[amh - b*LL];        // argmin of that row (same batch)
    float h1head = fmaxf(base - P[(size_t)amh*DD + d]*(1.0f/DEG) + Q[(size_t)(b*LL)*DD + d], 0.f);
    float h1am   = fmaxf(base - P[(size_t)am2*DD + d]*(1.0f/DEG) + Q[(size_t)amh*DD + d], 0.f);
    float agg = (colsum - h1am) * (1.0f/DEG);
    part[0][d] = agg * W2l[d] + h1head * W2r[d];
  }
  __syncthreads();
  if (t < 64) {
    float v = part[0][t] + part[0][t + 64];
#pragma unroll
    for (int msk = 32; msk > 0; msk >>= 1) v += __shfl_down(v, msk);
    if (t == 0) out[b] = v + b2l[0];
  }
  // ---- diff + targets (block 0) ----
  if (b == 0) {
    __shared__ float dred[256];
    if (t < 256) dred[t] = diffpart[t];
    __syncthreads();
    for (int off = 128; off > 0; off >>= 1) {
      if (t < off) dred[t] += dred[t+off];
      __syncthreads();
    }
    if (t == 0) out[4] = dred[0] / (float)((float)BB*LL*LL);
    if (t < 4) out[5+t] = targets[t*LL];
  }
}

extern "C" void kernel_launch(void* const* d_in, const int* in_sizes, int n_in,
                              void* d_out, int out_size, void* d_ws, size_t ws_size,
                              hipStream_t stream) {
  const float* inputs  = (const float*)d_in[0];
  const float* coords  = (const float*)d_in[1];
  const float* targets = (const float*)d_in[2];
  const float* cc      = (const float*)d_in[3];
  const float* Wc  = (const float*)d_in[5];
  const float* bc  = (const float*)d_in[6];
  const float* Wcc = (const float*)d_in[7];
  const float* bcc = (const float*)d_in[8];
  const float* Wa  = (const float*)d_in[9];
  const float* ba  = (const float*)d_in[10];
  const float* Wb  = (const float*)d_in[11];
  const float* bb  = (const float*)d_in[12];
  const float* W1l = (const float*)d_in[13];
  const float* b1l = (const float*)d_in[14];
  const float* W1r = (const float*)d_in[15];
  const float* W2l = (const float*)d_in[16];
  const float* b2l = (const float*)d_in[17];
  const float* W2r = (const float*)d_in[18];
  float* out = (float*)d_out;

  float* ws = (float*)d_ws;
  float* P  = ws;                               // NROW*DD
  float* Q  = ws + (size_t)NROW*DD;             // NROW*DD
  ushort* bfA  = (ushort*)(ws + (size_t)2*NROW*DD);
  ushort* bfB  = bfA  + (size_t)NROW*DD;
  ushort* bfAc = bfB  + (size_t)NROW*DD;
  ushort* bfBc = bfAc + (size_t)NROW*DD;
  float* xpart    = ws + (size_t)4*NROW*DD;     // 128*128
  float* diffpart = xpart + 128*DD;             // 256
  float* minval   = diffpart + 256;             // NROW*8
  int*   minidx   = (int*)(minval + (size_t)NROW*8);  // NROW*8

  k_front<<<dim3(128, 3), 256, 0, stream>>>(inputs, coords, cc, Wc, bc, Wcc, bcc,
                                            Wa, ba, Wb, bb, W1l, W1r,
                                            bfA, bfB, bfAc, bfBc, P, Q, xpart);
  k_adj  <<<dim3(8, 8, 4), 256, 0, stream>>>(bfA, bfB, bfAc, bfBc, diffpart, minval, minidx);
  k_tail <<<4, 1024, 0, stream>>>(P, Q, xpart, W1l, b1l, minval, minidx, diffpart, targets,
                                  W2l, b2l, W2r, out);
}